// Round 1
// baseline (903.894 us; speedup 1.0000x reference)
//
#include <hip/hip_runtime.h>
#include <hip/hip_bf16.h>
#include <stdint.h>

#define Bn 8
#define Dd 512
#define Nn 2048

typedef __attribute__((ext_vector_type(8))) short bf16x8;
typedef __attribute__((ext_vector_type(4))) float f32x4;
typedef __attribute__((ext_vector_type(4))) unsigned short ushort4v;

// ---- workspace layout (elements of ushort/bf16) ----
// Wh[3]: 786432 | Wl[3]: 786432 | xth: 8.39M | xtl | Qh | Ql | Kh | Kl | Vt
#define OFF_WH   ((size_t)0)
#define OFF_WL   ((size_t)786432)
#define OFF_XTH  ((size_t)1572864)
#define OFF_XTL  ((size_t)9961472)
#define OFF_QH   ((size_t)18350080)
#define OFF_QL   ((size_t)26738688)
#define OFF_KH   ((size_t)35127296)
#define OFF_KL   ((size_t)43515904)
#define OFF_VT   ((size_t)51904512)
// total 60293120 elems = 120.6 MB

static __device__ __forceinline__ unsigned short bf16rn(float x) {
  union { float f; uint32_t u; } v; v.f = x;
  uint32_t u = v.u;
  return (unsigned short)((u + 0x7FFFu + ((u >> 16) & 1u)) >> 16);
}
static __device__ __forceinline__ float bf2f(unsigned short h) {
  union { uint32_t u; float f; } v; v.u = ((uint32_t)h) << 16; return v.f;
}
static __device__ __forceinline__ f32x4 MFMA16(bf16x8 a, bf16x8 b, f32x4 c) {
  return __builtin_amdgcn_mfma_f32_16x16x32_bf16(a, b, c, 0, 0, 0);
}

// ---------------------------------------------------------------------------
// k0a: split weights into hi/lo bf16 planes
__global__ void wsplit_kernel(const float* __restrict__ Wq,
                              const float* __restrict__ Wk,
                              const float* __restrict__ Wv,
                              unsigned short* __restrict__ ws) {
  int idx = blockIdx.x * 256 + threadIdx.x;           // < 786432
  int p = idx >> 18;                                   // 0..2
  int e = idx & 262143;
  const float* W = (p == 0) ? Wq : ((p == 1) ? Wk : Wv);
  float v = W[e];
  unsigned short h = bf16rn(v);
  ws[OFF_WH + idx] = h;
  ws[OFF_WL + idx] = bf16rn(v - bf2f(h));
}

// ---------------------------------------------------------------------------
// k0b: transpose x [B][D][N] -> xt [B][N][D], split hi/lo
__global__ void xtsplit_kernel(const float* __restrict__ x,
                               unsigned short* __restrict__ ws) {
  __shared__ float t[32][33];
  int b = blockIdx.z, d0 = blockIdx.y * 32, n0 = blockIdx.x * 32;
  int tid = threadIdx.x;
  int r = tid >> 5, c = tid & 31;
  const float* xb = x + (size_t)b * Dd * Nn;
#pragma unroll
  for (int rr = 0; rr < 4; ++rr) {
    int dl = rr * 8 + r;
    t[dl][c] = xb[(size_t)(d0 + dl) * Nn + n0 + c];
  }
  __syncthreads();
  unsigned short* xh = ws + OFF_XTH + (size_t)b * Nn * Dd;
  unsigned short* xl = ws + OFF_XTL + (size_t)b * Nn * Dd;
#pragma unroll
  for (int rr = 0; rr < 4; ++rr) {
    int nl = rr * 8 + r;
    float v = t[c][nl];
    unsigned short h = bf16rn(v);
    int idx = (n0 + nl) * Dd + d0 + c;
    xh[idx] = h;
    xl[idx] = bf16rn(v - bf2f(h));
  }
}

// ---------------------------------------------------------------------------
// k1: projection GEMM. grid (N/64, B, 3[q,k,v]); 4 waves, each owns 128 j-cols.
// out[n][j] = sum_d xt[n][d] * W[j][d] + bias[j], split-bf16 (3 MFMA).
__global__ __launch_bounds__(256, 1) void proj_kernel(
    unsigned short* __restrict__ ws,
    const float* __restrict__ bq, const float* __restrict__ bk,
    const float* __restrict__ bv) {
  int z = blockIdx.z, b = blockIdx.y, n0 = blockIdx.x * 64;
  const unsigned short* Wh = ws + OFF_WH + (size_t)z * 262144;
  const unsigned short* Wl = ws + OFF_WL + (size_t)z * 262144;
  const unsigned short* xh = ws + OFF_XTH + (size_t)b * Nn * Dd;
  const unsigned short* xl = ws + OFF_XTL + (size_t)b * Nn * Dd;
  int tid = threadIdx.x;
  int w = tid >> 6, l = tid & 63;
  int l16 = l & 15, lq = l >> 4;
  int j0 = w * 128;

  f32x4 acc[32];
#pragma unroll
  for (int i = 0; i < 32; ++i) acc[i] = (f32x4){0.f, 0.f, 0.f, 0.f};

  for (int ks = 0; ks < 16; ++ks) {
    bf16x8 ah[4], al[4], bh[8], bl[8];
#pragma unroll
    for (int rt = 0; rt < 4; ++rt) {
      int off = (n0 + rt * 16 + l16) * Dd + ks * 32 + lq * 8;
      ah[rt] = *(const bf16x8*)(xh + off);
      al[rt] = *(const bf16x8*)(xl + off);
    }
#pragma unroll
    for (int ct = 0; ct < 8; ++ct) {
      int woff = (j0 + ct * 16 + l16) * Dd + ks * 32 + lq * 8;
      bh[ct] = *(const bf16x8*)(Wh + woff);
      bl[ct] = *(const bf16x8*)(Wl + woff);
    }
    // three passes -> each accumulator revisited at distance 32 (ILP)
#pragma unroll
    for (int ct = 0; ct < 8; ++ct)
#pragma unroll
      for (int rt = 0; rt < 4; ++rt)
        acc[rt * 8 + ct] = MFMA16(ah[rt], bh[ct], acc[rt * 8 + ct]);
#pragma unroll
    for (int ct = 0; ct < 8; ++ct)
#pragma unroll
      for (int rt = 0; rt < 4; ++rt)
        acc[rt * 8 + ct] = MFMA16(ah[rt], bl[ct], acc[rt * 8 + ct]);
#pragma unroll
    for (int ct = 0; ct < 8; ++ct)
#pragma unroll
      for (int rt = 0; rt < 4; ++rt)
        acc[rt * 8 + ct] = MFMA16(al[rt], bh[ct], acc[rt * 8 + ct]);
  }

  const float* bias = (z == 0) ? bq : ((z == 1) ? bk : bv);
  if (z < 2) {
    unsigned short* Oh = ws + ((z == 0) ? OFF_QH : OFF_KH) + (size_t)b * Nn * Dd;
    unsigned short* Ol = ws + ((z == 0) ? OFF_QL : OFF_KL) + (size_t)b * Nn * Dd;
#pragma unroll
    for (int ct = 0; ct < 8; ++ct) {
      int j = j0 + ct * 16 + l16;
      float bj = bias[j];
#pragma unroll
      for (int rt = 0; rt < 4; ++rt) {
        f32x4 a = acc[rt * 8 + ct];
#pragma unroll
        for (int r = 0; r < 4; ++r) {
          float v = a[r] + bj;
          int n = n0 + rt * 16 + lq * 4 + r;
          unsigned short h = bf16rn(v);
          Oh[n * Dd + j] = h;
          Ol[n * Dd + j] = bf16rn(v - bf2f(h));
        }
      }
    }
  } else {
    unsigned short* Vt = ws + OFF_VT + (size_t)b * Dd * Nn;
#pragma unroll
    for (int ct = 0; ct < 8; ++ct) {
      int j = j0 + ct * 16 + l16;
      float bj = bias[j];
#pragma unroll
      for (int rt = 0; rt < 4; ++rt) {
        f32x4 a = acc[rt * 8 + ct];
        ushort4v hv;
#pragma unroll
        for (int r = 0; r < 4; ++r) hv[r] = bf16rn(a[r] + bj);
        int nb = n0 + rt * 16 + lq * 4;
        *(ushort4v*)(Vt + (size_t)j * Nn + nb) = hv;  // 4 consecutive n
      }
    }
  }
}

// ---------------------------------------------------------------------------
// k2: fused flash attention. grid (N/64, B); 4 waves x 16 q-rows.
// LDS: K chunk [64][128] hi+lo (swizzled) | V [512][64] (swizzled) | P per-wave
#define LDS_KH 0
#define LDS_KL 8192
#define LDS_V  16384
#define LDS_P  49152   // 4 waves x 16 x 88

__global__ __launch_bounds__(256, 1) void attn_kernel(
    const unsigned short* __restrict__ ws, float* __restrict__ out) {
  __shared__ unsigned short lds[54784];
  int b = blockIdx.y, n0 = blockIdx.x * 64;
  int tid = threadIdx.x;
  int w = tid >> 6, l = tid & 63;
  int l16 = l & 15, lq = l >> 4;

  const unsigned short* Qh = ws + OFF_QH + (size_t)b * Nn * Dd;
  const unsigned short* Ql = ws + OFF_QL + (size_t)b * Nn * Dd;
  const unsigned short* Kh = ws + OFF_KH + (size_t)b * Nn * Dd;
  const unsigned short* Kl = ws + OFF_KL + (size_t)b * Nn * Dd;
  const unsigned short* Vt = ws + OFF_VT + (size_t)b * Dd * Nn;

  // Q fragments for this wave's 16 rows, full D, hi+lo (A-layout: row=l&15)
  bf16x8 qh[16], ql[16];
  {
    int qrow = n0 + w * 16 + l16;
#pragma unroll
    for (int ks = 0; ks < 16; ++ks) {
      int off = qrow * Dd + ks * 32 + lq * 8;
      qh[ks] = *(const bf16x8*)(Qh + off);
      ql[ks] = *(const bf16x8*)(Ql + off);
    }
  }

  f32x4 o[32];
#pragma unroll
  for (int i = 0; i < 32; ++i) o[i] = (f32x4){0.f, 0.f, 0.f, 0.f};
  float m[4], lsum[4];
#pragma unroll
  for (int r = 0; r < 4; ++r) { m[r] = -1e30f; lsum[r] = 0.f; }

  for (int kt = 0; kt < 32; ++kt) {
    int k0 = kt * 64;
    f32x4 s[4];
#pragma unroll
    for (int ct = 0; ct < 4; ++ct) s[ct] = (f32x4){0.f, 0.f, 0.f, 0.f};

    // ---- S = Q K^T over 4 d-chunks of 128
#pragma unroll
    for (int dc = 0; dc < 4; ++dc) {
      __syncthreads();
      // stage K chunk (hi+lo): 2048 x 16B slots, 8 per thread
#pragma unroll
      for (int j = 0; j < 8; ++j) {
        int slot = j * 256 + tid;
        int plane = slot >> 10;
        int s10 = slot & 1023;
        int row = s10 >> 4, c = s10 & 15;
        const unsigned short* src =
            (plane ? Kl : Kh) + (k0 + row) * Dd + dc * 128 + c * 8;
        bf16x8 t = *(const bf16x8*)src;
        int didx = (plane ? LDS_KL : LDS_KH) + row * 128 + ((c ^ (row & 7)) * 8);
        *(bf16x8*)(&lds[didx]) = t;
      }
      __syncthreads();
#pragma unroll
      for (int ks = 0; ks < 4; ++ks) {
        bf16x8 kh[4], kl[4];
#pragma unroll
        for (int ct = 0; ct < 4; ++ct) {
          int krow = ct * 16 + l16;
          int c = ks * 4 + lq;
          int idx = krow * 128 + ((c ^ (krow & 7)) * 8);
          kh[ct] = *(const bf16x8*)(&lds[LDS_KH + idx]);
          kl[ct] = *(const bf16x8*)(&lds[LDS_KL + idx]);
        }
        int ksq = dc * 4 + ks;
#pragma unroll
        for (int ct = 0; ct < 4; ++ct) s[ct] = MFMA16(qh[ksq], kh[ct], s[ct]);
#pragma unroll
        for (int ct = 0; ct < 4; ++ct) s[ct] = MFMA16(qh[ksq], kl[ct], s[ct]);
#pragma unroll
        for (int ct = 0; ct < 4; ++ct) s[ct] = MFMA16(ql[ksq], kh[ct], s[ct]);
      }
    }

    // ---- online softmax (wave-local; rows live in 16-lane groups)
    float scl[4];
#pragma unroll
    for (int r = 0; r < 4; ++r) {
      float tm = fmaxf(fmaxf(s[0][r], s[1][r]), fmaxf(s[2][r], s[3][r]));
      tm = fmaxf(tm, __shfl_xor(tm, 1, 16));
      tm = fmaxf(tm, __shfl_xor(tm, 2, 16));
      tm = fmaxf(tm, __shfl_xor(tm, 4, 16));
      tm = fmaxf(tm, __shfl_xor(tm, 8, 16));
      float mn = fmaxf(m[r], tm);
      scl[r] = __expf(m[r] - mn);
      float ps = 0.f;
#pragma unroll
      for (int ct = 0; ct < 4; ++ct) {
        float p = __expf(s[ct][r] - mn);
        s[ct][r] = p;
        ps += p;
      }
      ps += __shfl_xor(ps, 1, 16);
      ps += __shfl_xor(ps, 2, 16);
      ps += __shfl_xor(ps, 4, 16);
      ps += __shfl_xor(ps, 8, 16);
      lsum[r] = lsum[r] * scl[r] + ps;
      m[r] = mn;
    }
#pragma unroll
    for (int i = 0; i < 32; ++i) {
      f32x4 t = o[i];
      t[0] *= scl[0]; t[1] *= scl[1]; t[2] *= scl[2]; t[3] *= scl[3];
      o[i] = t;
    }
    // P -> per-wave LDS buffer (C-layout write, stride 88 breaks conflicts)
#pragma unroll
    for (int ct = 0; ct < 4; ++ct)
#pragma unroll
      for (int r = 0; r < 4; ++r)
        lds[LDS_P + w * 1408 + (lq * 4 + r) * 88 + ct * 16 + l16] =
            bf16rn(s[ct][r]);

    __syncthreads();  // P written; prev-iter V reads done
    // stage V [512][64] swizzled: 4096 slots, 16 per thread
#pragma unroll
    for (int j = 0; j < 16; ++j) {
      int slot = j * 256 + tid;
      int d = slot >> 3, c = slot & 7;
      bf16x8 t = *(const bf16x8*)(Vt + (size_t)d * Nn + k0 + c * 8);
      *(bf16x8*)(&lds[LDS_V + d * 64 + ((c ^ (d & 7)) * 8)]) = t;
    }
    __syncthreads();

    // ---- PV: O += P V
#pragma unroll
    for (int kks = 0; kks < 2; ++kks) {
      bf16x8 pa = *(const bf16x8*)(
          &lds[LDS_P + w * 1408 + l16 * 88 + kks * 32 + lq * 8]);
#pragma unroll
      for (int ct2 = 0; ct2 < 32; ++ct2) {
        int d = ct2 * 16 + l16;
        int c = kks * 4 + lq;
        bf16x8 vb = *(const bf16x8*)(&lds[LDS_V + d * 64 + ((c ^ (d & 7)) * 8)]);
        o[ct2] = MFMA16(pa, vb, o[ct2]);
      }
    }
  }

  // ---- epilogue: O /= lsum, store to out[b][d][n]
  float inv[4];
#pragma unroll
  for (int r = 0; r < 4; ++r) inv[r] = 1.0f / lsum[r];
  float* ob = out + (size_t)b * Dd * Nn;
  int nb = n0 + w * 16 + lq * 4;
#pragma unroll
  for (int ct2 = 0; ct2 < 32; ++ct2) {
    int d = ct2 * 16 + l16;
    f32x4 t = o[ct2];
    t[0] *= inv[0]; t[1] *= inv[1]; t[2] *= inv[2]; t[3] *= inv[3];
    *(f32x4*)(ob + (size_t)d * Nn + nb) = t;
  }
}

// ---------------------------------------------------------------------------
extern "C" void kernel_launch(void* const* d_in, const int* in_sizes, int n_in,
                              void* d_out, int out_size, void* d_ws,
                              size_t ws_size, hipStream_t stream) {
  const float* x  = (const float*)d_in[0];
  const float* Wq = (const float*)d_in[1];
  const float* bq = (const float*)d_in[2];
  const float* Wk = (const float*)d_in[3];
  const float* bk = (const float*)d_in[4];
  const float* Wv = (const float*)d_in[5];
  const float* bv = (const float*)d_in[6];
  unsigned short* ws = (unsigned short*)d_ws;
  float* out = (float*)d_out;

  hipLaunchKernelGGL(wsplit_kernel, dim3(3072), dim3(256), 0, stream,
                     Wq, Wk, Wv, ws);
  hipLaunchKernelGGL(xtsplit_kernel, dim3(Nn / 32, Dd / 32, Bn), dim3(256), 0,
                     stream, x, ws);
  hipLaunchKernelGGL(proj_kernel, dim3(Nn / 64, Bn, 3), dim3(256), 0, stream,
                     ws, bq, bk, bv);
  hipLaunchKernelGGL(attn_kernel, dim3(Nn / 64, Bn), dim3(256), 0, stream,
                     ws, out);
}